// Round 2
// baseline (391.494 us; speedup 1.0000x reference)
//
#include <hip/hip_runtime.h>
#include <hip/hip_bf16.h>

// Problem sizes
#define NB 4
#define DIMC 64
#define C2 256
#define HFC 128
#define HH 256
#define WW 256
#define HW (HH * WW)

typedef __attribute__((ext_vector_type(8))) short short8;
typedef __attribute__((ext_vector_type(4))) float f32x4;

__device__ __forceinline__ f32x4 mfma16(short8 a, short8 b, f32x4 c) {
  return __builtin_amdgcn_mfma_f32_16x16x32_bf16(a, b, c, 0, 0, 0);
}

__device__ __forceinline__ short f2bs(float f) {
  __hip_bfloat16 h = __float2bfloat16(f);
  union { __hip_bfloat16 h; short s; } u; u.h = h;
  return u.s;
}

// ---------------------------------------------------------------------------
// prep: build (a) per-channel 64x64 spectral matrices from fft_filt, as MFMA
// A-fragments; (b) w_in / w_out bf16 A-fragments.
// Fragment-major layout: [mblk][kblk][lane(64)][j(8)] so a lane's 8 bf16
// A[m=lane&15][k=kblk*32+(lane>>4)*8+j] sit at byte offset lane*16.
// ---------------------------------------------------------------------------
__global__ __launch_bounds__(64) void prep_kernel(
    const float* __restrict__ w_in, const float* __restrict__ fft,
    const float* __restrict__ w_out, __hip_bfloat16* __restrict__ A1,
    __hip_bfloat16* __restrict__ A2, __hip_bfloat16* __restrict__ Mf) {
  int blk = blockIdx.x;
  int l = threadIdx.x;
  int mm = l & 15, qj = l >> 4;
  if (blk < C2) {
    __shared__ float Feff[64];
    __shared__ float kc[64];
    __shared__ float ct[8];
    if (l < 8) {
      const float s = 0.70710678118654752f;
      const float v0[8] = {1.f, s, 0.f, -s, -1.f, -s, 0.f, s};
      ct[l] = v0[l];
    }
    int c = blk;
    const float* f = fft + c * 40;  // [u][v], v in [0,5)
    int u = l >> 3, v = l & 7;
    int um = (8 - u) & 7;
    float val;
    if (v <= 4) {
      val = f[u * 5 + v];
      // pocketfft c2r ignores imag of DC/Nyquist bins -> u-symmetrize
      if (v == 0 || v == 4) val = 0.5f * (val + f[um * 5 + v]);
    } else {
      val = f[um * 5 + (8 - v)];  // Hermitian extension (filter is real)
    }
    Feff[l] = val;
    __syncthreads();
    int dy = l >> 3, dx = l & 7;
    float s = 0.f;
    for (int uu = 0; uu < 8; ++uu)
      for (int vv = 0; vv < 8; ++vv)
        s += Feff[uu * 8 + vv] * ct[(uu * dy + vv * dx) & 7];
    kc[l] = s * (1.f / 64.f);
    __syncthreads();
    for (int mb = 0; mb < 4; ++mb) {
      int p = mb * 16 + mm;
      int py = p >> 3, px = p & 7;
      for (int kb = 0; kb < 2; ++kb)
        for (int j = 0; j < 8; ++j) {
          int q = kb * 32 + qj * 8 + j;
          int qy = q >> 3, qx = q & 7;
          float kv = kc[((py - qy) & 7) * 8 + ((px - qx) & 7)];
          Mf[(size_t)c * 4096 + (size_t)((mb * 2 + kb) * 64 + l) * 8 + j] =
              __float2bfloat16(kv);
        }
    }
  } else if (blk == C2) {
    // w_in (256x64) fragments: 16 mblk x 2 kblk
    for (int mb = 0; mb < 16; ++mb)
      for (int kb = 0; kb < 2; ++kb)
        for (int j = 0; j < 8; ++j) {
          int m = mb * 16 + mm, k = kb * 32 + qj * 8 + j;
          A1[(size_t)((mb * 2 + kb) * 64 + l) * 8 + j] =
              __float2bfloat16(w_in[m * 64 + k]);
        }
  } else {
    // w_out (64x128) fragments: 4 mblk x 4 kblk
    for (int mb = 0; mb < 4; ++mb)
      for (int kb = 0; kb < 4; ++kb)
        for (int j = 0; j < 8; ++j) {
          int m = mb * 16 + mm, k = kb * 32 + qj * 8 + j;
          A2[(size_t)((mb * 4 + kb) * 64 + l) * 8 + j] =
              __float2bfloat16(w_out[m * 128 + k]);
        }
  }
}

// ---------------------------------------------------------------------------
// gemm1 (per batch): h[c][pix] = sum_d w_in[c][d] * x[d][pix], bf16 out.
// Block: M=256 (all channels) x N=64 pixels, K=64 whole.
// x tile staged to LDS in B-fragment-major order (one b128 write/thread/half).
// ---------------------------------------------------------------------------
__global__ __launch_bounds__(256) void gemm1_kernel(
    const float* __restrict__ x, const __hip_bfloat16* __restrict__ A1,
    __hip_bfloat16* __restrict__ h1) {
  __shared__ short Bt[8 * 64 * 8];  // [kblk*4+nblk][lane][j] = 8 KiB
  int n0 = blockIdx.x * 64;
  int t = threadIdx.x;
  int n = t & 63, dgrp = t >> 6;
  int nblk = n >> 4, nn = n & 15;
  const float* xb = x + n0 + n;
#pragma unroll
  for (int s = 0; s < 2; ++s) {
    int jb = dgrp + s * 4;  // [0,8): d-block of 8
    int kb = jb >> 2, quad = jb & 3;
    short8 pk;
#pragma unroll
    for (int j = 0; j < 8; ++j) pk[j] = f2bs(xb[(size_t)(jb * 8 + j) * HW]);
    *reinterpret_cast<short8*>(&Bt[((kb * 4 + nblk) * 64 + quad * 16 + nn) * 8]) = pk;
  }
  __syncthreads();
  int w = t >> 6, l = t & 63;
  const short8* A1v = reinterpret_cast<const short8*>(A1);
  short8 af[4][2];
#pragma unroll
  for (int mb = 0; mb < 4; ++mb)
#pragma unroll
    for (int kb = 0; kb < 2; ++kb)
      af[mb][kb] = A1v[((w * 4 + mb) * 2 + kb) * 64 + l];
  const short8* Bv = reinterpret_cast<const short8*>(Bt);
  f32x4 acc[4][4];
#pragma unroll
  for (int i = 0; i < 4; ++i)
#pragma unroll
    for (int j = 0; j < 4; ++j) acc[i][j] = (f32x4){0.f, 0.f, 0.f, 0.f};
#pragma unroll
  for (int nb = 0; nb < 4; ++nb) {
    short8 b0 = Bv[(0 * 4 + nb) * 64 + l];
    short8 b1 = Bv[(1 * 4 + nb) * 64 + l];
#pragma unroll
    for (int mb = 0; mb < 4; ++mb) {
      acc[mb][nb] = mfma16(af[mb][0], b0, acc[mb][nb]);
      acc[mb][nb] = mfma16(af[mb][1], b1, acc[mb][nb]);
    }
  }
  int quad = l >> 4, ln = l & 15;
#pragma unroll
  for (int mb = 0; mb < 4; ++mb)
#pragma unroll
    for (int nb = 0; nb < 4; ++nb)
#pragma unroll
      for (int r = 0; r < 4; ++r) {
        int m = w * 64 + mb * 16 + quad * 4 + r;
        int pix = n0 + nb * 16 + ln;
        h1[(size_t)m * HW + pix] = __float2bfloat16(acc[mb][nb][r]);
      }
}

// ---------------------------------------------------------------------------
// spectral (per batch, IN-PLACE): per channel c, patch p: h <- M_c @ h.
// Block: one channel x 256 patches; each block reads only its own patches
// (all reads precede all writes within the block), so in-place is race-free.
// B-fragments read directly from image layout (patch row = 16 contig bytes).
// ---------------------------------------------------------------------------
__global__ __launch_bounds__(256) void spectral_kernel(
    __hip_bfloat16* hb, const __hip_bfloat16* __restrict__ Mf) {
  int c = blockIdx.y;
  int t0 = blockIdx.x * 256;
  int tid = threadIdx.x;
  int w = tid >> 6, l = tid & 63;
  int quad = l >> 4, ln = l & 15;
  const short8* Mv = reinterpret_cast<const short8*>(Mf + (size_t)c * 4096);
  short8 af[4][2];
#pragma unroll
  for (int mb = 0; mb < 4; ++mb)
#pragma unroll
    for (int kb = 0; kb < 2; ++kb) af[mb][kb] = Mv[(mb * 2 + kb) * 64 + l];
  f32x4 acc[4][4];
#pragma unroll
  for (int i = 0; i < 4; ++i)
#pragma unroll
    for (int j = 0; j < 4; ++j) acc[i][j] = (f32x4){0.f, 0.f, 0.f, 0.f};
#pragma unroll
  for (int nb = 0; nb < 4; ++nb) {
    int tp = t0 + w * 64 + nb * 16 + ln;  // patch id: Py*32 + Px (per batch)
    int Py = (tp >> 5) & 31, Px = tp & 31;
    const __hip_bfloat16* base = hb + ((size_t)c * HH + Py * 8) * WW + Px * 8;
    short8 bf0 = *reinterpret_cast<const short8*>(base + (size_t)quad * WW);
    short8 bf1 = *reinterpret_cast<const short8*>(base + (size_t)(4 + quad) * WW);
#pragma unroll
    for (int mb = 0; mb < 4; ++mb) {
      acc[mb][nb] = mfma16(af[mb][0], bf0, acc[mb][nb]);
      acc[mb][nb] = mfma16(af[mb][1], bf1, acc[mb][nb]);
    }
  }
  __syncthreads();  // all reads of this block's patches complete before writes
#pragma unroll
  for (int nb = 0; nb < 4; ++nb) {
    int tp = t0 + w * 64 + nb * 16 + ln;
    int Py = (tp >> 5) & 31, Px = tp & 31;
    __hip_bfloat16* ob = hb + ((size_t)c * HH + Py * 8) * WW + Px * 8;
#pragma unroll
    for (int mb = 0; mb < 4; ++mb)
#pragma unroll
      for (int r = 0; r < 4; ++r) {
        int p = mb * 16 + quad * 4 + r;
        ob[(p >> 3) * WW + (p & 7)] = __float2bfloat16(acc[mb][nb][r]);
      }
  }
}

// ---------------------------------------------------------------------------
// dwgelu (per batch): depthwise 3x3 (SAME) on h, then g = gelu_exact(x1)*x2,
// written in GEMM2 B-fragment-major order (one b128 store per thread).
// Thread: one pixel x 8 hf-channels.
// ---------------------------------------------------------------------------
__global__ __launch_bounds__(256) void dwgelu_kernel(
    const __hip_bfloat16* __restrict__ h2, const float* __restrict__ w_dw,
    __hip_bfloat16* __restrict__ gf) {
  int jb = blockIdx.x;  // [0,16): hf block of 8
  int y = blockIdx.y;
  int xx = threadIdx.x;  // [0,256): pixel x
  float a1[8], a2[8];
#pragma unroll
  for (int j = 0; j < 8; ++j) { a1[j] = 0.f; a2[j] = 0.f; }
#pragma unroll
  for (int dy = -1; dy <= 1; ++dy) {
    int yy = y + dy;
    if (yy < 0 || yy >= HH) continue;
#pragma unroll
    for (int dx = -1; dx <= 1; ++dx) {
      int xi = xx + dx;
      if (xi < 0 || xi >= WW) continue;
      int kk = (dy + 1) * 3 + (dx + 1);
#pragma unroll
      for (int j = 0; j < 8; ++j) {
        int c1 = jb * 8 + j;
        float v1 = __bfloat162float(h2[((size_t)c1 * HH + yy) * WW + xi]);
        float v2 =
            __bfloat162float(h2[((size_t)(c1 + HFC) * HH + yy) * WW + xi]);
        a1[j] += v1 * w_dw[c1 * 9 + kk];
        a2[j] += v2 * w_dw[(c1 + HFC) * 9 + kk];
      }
    }
  }
  short8 pk;
#pragma unroll
  for (int j = 0; j < 8; ++j) {
    float u = a1[j];
    float g = 0.5f * u * (1.f + erff(u * 0.70710678118654752f));
    pk[j] = f2bs(g * a2[j]);
  }
  int pix = y * WW + xx;
  int pixblk = pix >> 4, nn = pix & 15;
  int kb = jb >> 2, quad = jb & 3;
  reinterpret_cast<short8*>(gf)[((size_t)pixblk * 4 + kb) * 64 + quad * 16 + nn] =
      pk;
}

// ---------------------------------------------------------------------------
// gemm2 (per batch): out[o][pix] = sum_hf w_out[o][hf] * g[hf][pix], fp32 out.
// Block: M=64 x N=256 pixels, K=128. No LDS: fragments load coalesced.
// ---------------------------------------------------------------------------
__global__ __launch_bounds__(256) void gemm2_kernel(
    const __hip_bfloat16* __restrict__ gf, const __hip_bfloat16* __restrict__ A2,
    float* __restrict__ out) {
  int pix0 = blockIdx.x * 256;
  int tid = threadIdx.x;
  int w = tid >> 6, l = tid & 63;
  int quad = l >> 4, ln = l & 15;
  const short8* A2v = reinterpret_cast<const short8*>(A2);
  short8 af[4][4];
#pragma unroll
  for (int mb = 0; mb < 4; ++mb)
#pragma unroll
    for (int kb = 0; kb < 4; ++kb) af[mb][kb] = A2v[(mb * 4 + kb) * 64 + l];
  const short8* gv = reinterpret_cast<const short8*>(gf);
  f32x4 acc[4][4];
#pragma unroll
  for (int i = 0; i < 4; ++i)
#pragma unroll
    for (int j = 0; j < 4; ++j) acc[i][j] = (f32x4){0.f, 0.f, 0.f, 0.f};
#pragma unroll
  for (int nb = 0; nb < 4; ++nb) {
    size_t pixblk = (size_t)blockIdx.x * 16 + w * 4 + nb;
    short8 bf[4];
#pragma unroll
    for (int kb = 0; kb < 4; ++kb) bf[kb] = gv[(pixblk * 4 + kb) * 64 + l];
#pragma unroll
    for (int mb = 0; mb < 4; ++mb)
#pragma unroll
      for (int kb = 0; kb < 4; ++kb)
        acc[mb][nb] = mfma16(af[mb][kb], bf[kb], acc[mb][nb]);
  }
#pragma unroll
  for (int mb = 0; mb < 4; ++mb)
#pragma unroll
    for (int nb = 0; nb < 4; ++nb)
#pragma unroll
      for (int r = 0; r < 4; ++r) {
        int o = mb * 16 + quad * 4 + r;
        int pix = pix0 + w * 64 + nb * 16 + ln;
        out[(size_t)o * HW + pix] = acc[mb][nb][r];
      }
}

// ---------------------------------------------------------------------------
// Workspace layout (bytes), per-batch processing to keep footprint small:
//   0          A1 (w_in frags)    32768
//   32768      A2 (w_out frags)   16384
//   49152      Mf (spectral mats) 2097152
//   2146304    gf (g frags, 1 b)  16777216
//   18923520   h  (bf16, 1 batch) 33554432
// total 52,477,952 B (~50 MiB). All offsets 16B-aligned.
// ---------------------------------------------------------------------------
extern "C" void kernel_launch(void* const* d_in, const int* in_sizes, int n_in,
                              void* d_out, int out_size, void* d_ws,
                              size_t ws_size, hipStream_t stream) {
  const float* x = (const float*)d_in[0];
  const float* w_in = (const float*)d_in[1];
  const float* w_dw = (const float*)d_in[2];
  const float* fft = (const float*)d_in[3];
  const float* w_out = (const float*)d_in[4];
  float* out = (float*)d_out;
  char* ws = (char*)d_ws;
  __hip_bfloat16* A1 = (__hip_bfloat16*)(ws);
  __hip_bfloat16* A2 = (__hip_bfloat16*)(ws + 32768);
  __hip_bfloat16* Mf = (__hip_bfloat16*)(ws + 49152);
  __hip_bfloat16* gf = (__hip_bfloat16*)(ws + 2146304);
  __hip_bfloat16* h = (__hip_bfloat16*)(ws + 18923520);

  prep_kernel<<<258, 64, 0, stream>>>(w_in, fft, w_out, A1, A2, Mf);
  for (int b = 0; b < NB; ++b) {
    const float* xb = x + (size_t)b * DIMC * HW;
    float* outb = out + (size_t)b * DIMC * HW;
    gemm1_kernel<<<1024, 256, 0, stream>>>(xb, A1, h);
    spectral_kernel<<<dim3(4, C2), 256, 0, stream>>>(h, Mf);
    dwgelu_kernel<<<dim3(16, HH), 256, 0, stream>>>(h, w_dw, gf);
    gemm2_kernel<<<256, 256, 0, stream>>>(gf, A2, outb);
  }
}

// Round 3
// 339.839 us; speedup vs baseline: 1.1520x; 1.1520x over previous
//
#include <hip/hip_runtime.h>
#include <hip/hip_bf16.h>

// Problem sizes
#define NB 4
#define DIMC 64
#define C2 256
#define HFC 128
#define HH 256
#define WW 256
#define HW (HH * WW)

typedef __attribute__((ext_vector_type(8))) short short8;
typedef __attribute__((ext_vector_type(4))) float f32x4;

__device__ __forceinline__ f32x4 mfma16(short8 a, short8 b, f32x4 c) {
  return __builtin_amdgcn_mfma_f32_16x16x32_bf16(a, b, c, 0, 0, 0);
}

__device__ __forceinline__ short f2bs(float f) {
  __hip_bfloat16 h = __float2bfloat16(f);
  union { __hip_bfloat16 h; short s; } u; u.h = h;
  return u.s;
}

__device__ __forceinline__ float bs2f(short s) {
  union { float f; unsigned u; } v;
  v.u = ((unsigned)(unsigned short)s) << 16;
  return v.f;
}

// ---------------------------------------------------------------------------
// prep: build (a) per-channel 64x64 spectral matrices from fft_filt, as MFMA
// A-fragments; (b) w_in / w_out bf16 A-fragments.
// Fragment-major layout: [mblk][kblk][lane(64)][j(8)] so a lane's 8 bf16
// A[m=lane&15][k=kblk*32+(lane>>4)*8+j] sit at byte offset lane*16.
// ---------------------------------------------------------------------------
__global__ __launch_bounds__(64) void prep_kernel(
    const float* __restrict__ w_in, const float* __restrict__ fft,
    const float* __restrict__ w_out, __hip_bfloat16* __restrict__ A1,
    __hip_bfloat16* __restrict__ A2, __hip_bfloat16* __restrict__ Mf) {
  int blk = blockIdx.x;
  int l = threadIdx.x;
  int mm = l & 15, qj = l >> 4;
  if (blk < C2) {
    __shared__ float Feff[64];
    __shared__ float kc[64];
    __shared__ float ct[8];
    if (l < 8) {
      const float s = 0.70710678118654752f;
      const float v0[8] = {1.f, s, 0.f, -s, -1.f, -s, 0.f, s};
      ct[l] = v0[l];
    }
    int c = blk;
    const float* f = fft + c * 40;  // [u][v], v in [0,5)
    int u = l >> 3, v = l & 7;
    int um = (8 - u) & 7;
    float val;
    if (v <= 4) {
      val = f[u * 5 + v];
      // pocketfft c2r ignores imag of DC/Nyquist bins -> u-symmetrize
      if (v == 0 || v == 4) val = 0.5f * (val + f[um * 5 + v]);
    } else {
      val = f[um * 5 + (8 - v)];  // Hermitian extension (filter is real)
    }
    Feff[l] = val;
    __syncthreads();
    int dy = l >> 3, dx = l & 7;
    float s = 0.f;
    for (int uu = 0; uu < 8; ++uu)
      for (int vv = 0; vv < 8; ++vv)
        s += Feff[uu * 8 + vv] * ct[(uu * dy + vv * dx) & 7];
    kc[l] = s * (1.f / 64.f);
    __syncthreads();
    for (int mb = 0; mb < 4; ++mb) {
      int p = mb * 16 + mm;
      int py = p >> 3, px = p & 7;
      for (int kb = 0; kb < 2; ++kb)
        for (int j = 0; j < 8; ++j) {
          int q = kb * 32 + qj * 8 + j;
          int qy = q >> 3, qx = q & 7;
          float kv = kc[((py - qy) & 7) * 8 + ((px - qx) & 7)];
          Mf[(size_t)c * 4096 + (size_t)((mb * 2 + kb) * 64 + l) * 8 + j] =
              __float2bfloat16(kv);
        }
    }
  } else if (blk == C2) {
    // w_in (256x64) fragments: 16 mblk x 2 kblk
    for (int mb = 0; mb < 16; ++mb)
      for (int kb = 0; kb < 2; ++kb)
        for (int j = 0; j < 8; ++j) {
          int m = mb * 16 + mm, k = kb * 32 + qj * 8 + j;
          A1[(size_t)((mb * 2 + kb) * 64 + l) * 8 + j] =
              __float2bfloat16(w_in[m * 64 + k]);
        }
  } else {
    // w_out (64x128) fragments: 4 mblk x 4 kblk
    for (int mb = 0; mb < 4; ++mb)
      for (int kb = 0; kb < 4; ++kb)
        for (int j = 0; j < 8; ++j) {
          int m = mb * 16 + mm, k = kb * 32 + qj * 8 + j;
          A2[(size_t)((mb * 4 + kb) * 64 + l) * 8 + j] =
              __float2bfloat16(w_out[m * 128 + k]);
        }
  }
}

// ---------------------------------------------------------------------------
// gemm1 (per batch): h[c][pix] = sum_d w_in[c][d] * x[d][pix], bf16 out.
// ---------------------------------------------------------------------------
__global__ __launch_bounds__(256) void gemm1_kernel(
    const float* __restrict__ x, const __hip_bfloat16* __restrict__ A1,
    __hip_bfloat16* __restrict__ h1) {
  __shared__ short Bt[8 * 64 * 8];  // [kblk*4+nblk][lane][j] = 8 KiB
  int n0 = blockIdx.x * 64;
  int t = threadIdx.x;
  int n = t & 63, dgrp = t >> 6;
  int nblk = n >> 4, nn = n & 15;
  const float* xb = x + n0 + n;
#pragma unroll
  for (int s = 0; s < 2; ++s) {
    int jb = dgrp + s * 4;  // [0,8): d-block of 8
    int kb = jb >> 2, quad = jb & 3;
    short8 pk;
#pragma unroll
    for (int j = 0; j < 8; ++j) pk[j] = f2bs(xb[(size_t)(jb * 8 + j) * HW]);
    *reinterpret_cast<short8*>(&Bt[((kb * 4 + nblk) * 64 + quad * 16 + nn) * 8]) = pk;
  }
  __syncthreads();
  int w = t >> 6, l = t & 63;
  const short8* A1v = reinterpret_cast<const short8*>(A1);
  short8 af[4][2];
#pragma unroll
  for (int mb = 0; mb < 4; ++mb)
#pragma unroll
    for (int kb = 0; kb < 2; ++kb)
      af[mb][kb] = A1v[((w * 4 + mb) * 2 + kb) * 64 + l];
  const short8* Bv = reinterpret_cast<const short8*>(Bt);
  f32x4 acc[4][4];
#pragma unroll
  for (int i = 0; i < 4; ++i)
#pragma unroll
    for (int j = 0; j < 4; ++j) acc[i][j] = (f32x4){0.f, 0.f, 0.f, 0.f};
#pragma unroll
  for (int nb = 0; nb < 4; ++nb) {
    short8 b0 = Bv[(0 * 4 + nb) * 64 + l];
    short8 b1 = Bv[(1 * 4 + nb) * 64 + l];
#pragma unroll
    for (int mb = 0; mb < 4; ++mb) {
      acc[mb][nb] = mfma16(af[mb][0], b0, acc[mb][nb]);
      acc[mb][nb] = mfma16(af[mb][1], b1, acc[mb][nb]);
    }
  }
  int quad = l >> 4, ln = l & 15;
#pragma unroll
  for (int mb = 0; mb < 4; ++mb)
#pragma unroll
    for (int nb = 0; nb < 4; ++nb)
#pragma unroll
      for (int r = 0; r < 4; ++r) {
        int m = w * 64 + mb * 16 + quad * 4 + r;
        int pix = n0 + nb * 16 + ln;
        h1[(size_t)m * HW + pix] = __float2bfloat16(acc[mb][nb][r]);
      }
}

// ---------------------------------------------------------------------------
// spectral (per batch, IN-PLACE): per channel c, patch p: h <- M_c @ h.
// ---------------------------------------------------------------------------
__global__ __launch_bounds__(256) void spectral_kernel(
    __hip_bfloat16* hb, const __hip_bfloat16* __restrict__ Mf) {
  int c = blockIdx.y;
  int t0 = blockIdx.x * 256;
  int tid = threadIdx.x;
  int w = tid >> 6, l = tid & 63;
  int quad = l >> 4, ln = l & 15;
  const short8* Mv = reinterpret_cast<const short8*>(Mf + (size_t)c * 4096);
  short8 af[4][2];
#pragma unroll
  for (int mb = 0; mb < 4; ++mb)
#pragma unroll
    for (int kb = 0; kb < 2; ++kb) af[mb][kb] = Mv[(mb * 2 + kb) * 64 + l];
  f32x4 acc[4][4];
#pragma unroll
  for (int i = 0; i < 4; ++i)
#pragma unroll
    for (int j = 0; j < 4; ++j) acc[i][j] = (f32x4){0.f, 0.f, 0.f, 0.f};
#pragma unroll
  for (int nb = 0; nb < 4; ++nb) {
    int tp = t0 + w * 64 + nb * 16 + ln;  // patch id: Py*32 + Px (per batch)
    int Py = (tp >> 5) & 31, Px = tp & 31;
    const __hip_bfloat16* base = hb + ((size_t)c * HH + Py * 8) * WW + Px * 8;
    short8 bf0 = *reinterpret_cast<const short8*>(base + (size_t)quad * WW);
    short8 bf1 = *reinterpret_cast<const short8*>(base + (size_t)(4 + quad) * WW);
#pragma unroll
    for (int mb = 0; mb < 4; ++mb) {
      acc[mb][nb] = mfma16(af[mb][0], bf0, acc[mb][nb]);
      acc[mb][nb] = mfma16(af[mb][1], bf1, acc[mb][nb]);
    }
  }
  __syncthreads();  // all reads of this block's patches complete before writes
#pragma unroll
  for (int nb = 0; nb < 4; ++nb) {
    int tp = t0 + w * 64 + nb * 16 + ln;
    int Py = (tp >> 5) & 31, Px = tp & 31;
    __hip_bfloat16* ob = hb + ((size_t)c * HH + Py * 8) * WW + Px * 8;
#pragma unroll
    for (int mb = 0; mb < 4; ++mb)
#pragma unroll
      for (int r = 0; r < 4; ++r) {
        int p = mb * 16 + quad * 4 + r;
        ob[(p >> 3) * WW + (p & 7)] = __float2bfloat16(acc[mb][nb][r]);
      }
  }
}

// ---------------------------------------------------------------------------
// dwgelu v2 (per batch): depthwise 3x3 (SAME) + gelu-gate, x-vectorized.
// Block = (jb in [0,16), y-strip of 4 rows). Thread t: j = t&7 (channel pair
// c1 = jb*8+j, c2 = c1+128), xg = t>>3 (8-px x-chunk). Thread computes both
// convs in fp32 over 4 rows x 8 px, gates in-register, then the block
// repacks through XOR-swizzled LDS into gf B-fragment layout (8 channels
// per 16B) with 4 coalesced b128 stores/thread.
// ---------------------------------------------------------------------------
__global__ __launch_bounds__(256) void dwgelu_kernel(
    const __hip_bfloat16* __restrict__ h2, const float* __restrict__ w_dw,
    __hip_bfloat16* __restrict__ gf) {
  __shared__ short ldsG[4 * 256 * 8];  // 16 KiB, [B=r*256+px (xor-swz)][j]
  int jb = blockIdx.x;       // [0,16)
  int strip = blockIdx.y;    // [0,64): rows y0..y0+3
  int y0 = strip * 4;
  int t = threadIdx.x;
  int j = t & 7, xg = t >> 3;  // xg in [0,32)
  int x0 = xg * 8;
  int c1 = jb * 8 + j, c2 = c1 + HFC;

  float wd1[9], wd2[9];
#pragma unroll
  for (int k = 0; k < 9; ++k) {
    wd1[k] = w_dw[c1 * 9 + k];
    wd2[k] = w_dw[c2 * 9 + k];
  }

  float acc1[4][8], acc2[4][8];
#pragma unroll
  for (int r = 0; r < 4; ++r)
#pragma unroll
    for (int i = 0; i < 8; ++i) { acc1[r][i] = 0.f; acc2[r][i] = 0.f; }

#pragma unroll
  for (int ir = -1; ir <= 4; ++ir) {
    int yy = y0 + ir;
    bool valid = (yy >= 0) && (yy < HH);
    float f1[10], f2[10];
    if (valid) {
      const __hip_bfloat16* r1 = h2 + ((size_t)c1 * HH + yy) * WW;
      const __hip_bfloat16* r2 = h2 + ((size_t)c2 * HH + yy) * WW;
      short8 v1 = *reinterpret_cast<const short8*>(r1 + x0);
      short8 v2 = *reinterpret_cast<const short8*>(r2 + x0);
#pragma unroll
      for (int i = 0; i < 8; ++i) { f1[i + 1] = bs2f(v1[i]); f2[i + 1] = bs2f(v2[i]); }
      f1[0] = (x0 > 0) ? __bfloat162float(r1[x0 - 1]) : 0.f;
      f2[0] = (x0 > 0) ? __bfloat162float(r2[x0 - 1]) : 0.f;
      f1[9] = (x0 + 8 < WW) ? __bfloat162float(r1[x0 + 8]) : 0.f;
      f2[9] = (x0 + 8 < WW) ? __bfloat162float(r2[x0 + 8]) : 0.f;
    } else {
#pragma unroll
      for (int i = 0; i < 10; ++i) { f1[i] = 0.f; f2[i] = 0.f; }
    }
#pragma unroll
    for (int dy = -1; dy <= 1; ++dy) {
      int r = ir - dy;
      if (r < 0 || r >= 4) continue;
      int ky = dy + 1;
#pragma unroll
      for (int i = 0; i < 8; ++i) {
        acc1[r][i] += f1[i] * wd1[ky * 3] + f1[i + 1] * wd1[ky * 3 + 1] +
                      f1[i + 2] * wd1[ky * 3 + 2];
        acc2[r][i] += f2[i] * wd2[ky * 3] + f2[i + 1] * wd2[ky * 3 + 1] +
                      f2[i + 2] * wd2[ky * 3 + 2];
      }
    }
  }

  // gate + write to swizzled LDS (scalar u16 writes: 2 lanes/bank = free)
#pragma unroll
  for (int r = 0; r < 4; ++r)
#pragma unroll
    for (int i = 0; i < 8; ++i) {
      float u = acc1[r][i];
      float g = 0.5f * u * (1.f + erff(u * 0.70710678118654752f));
      int B = r * 256 + x0 + i;
      int Bs = B ^ ((B >> 3) & 7);
      ldsG[Bs * 8 + j] = f2bs(g * acc2[r][i]);
    }
  __syncthreads();

  // repack: 4 b128 reads (conflict-free) + 4 coalesced b128 stores
  int kb = jb >> 2, quad = jb & 3;
  short8* gfv = reinterpret_cast<short8*>(gf);
#pragma unroll
  for (int k = 0; k < 4; ++k) {
    int B = k * 256 + t;  // r = B>>8, px = B&255
    int Bs = B ^ ((B >> 3) & 7);
    short8 v = *reinterpret_cast<const short8*>(&ldsG[Bs * 8]);
    int pix = (y0 + (B >> 8)) * WW + (B & 255);
    gfv[((size_t)(pix >> 4) * 4 + kb) * 64 + quad * 16 + (pix & 15)] = v;
  }
}

// ---------------------------------------------------------------------------
// gemm2 (per batch): out[o][pix] = sum_hf w_out[o][hf] * g[hf][pix], fp32 out.
// ---------------------------------------------------------------------------
__global__ __launch_bounds__(256) void gemm2_kernel(
    const __hip_bfloat16* __restrict__ gf, const __hip_bfloat16* __restrict__ A2,
    float* __restrict__ out) {
  int pix0 = blockIdx.x * 256;
  int tid = threadIdx.x;
  int w = tid >> 6, l = tid & 63;
  int quad = l >> 4, ln = l & 15;
  const short8* A2v = reinterpret_cast<const short8*>(A2);
  short8 af[4][4];
#pragma unroll
  for (int mb = 0; mb < 4; ++mb)
#pragma unroll
    for (int kb = 0; kb < 4; ++kb) af[mb][kb] = A2v[(mb * 4 + kb) * 64 + l];
  const short8* gv = reinterpret_cast<const short8*>(gf);
  f32x4 acc[4][4];
#pragma unroll
  for (int i = 0; i < 4; ++i)
#pragma unroll
    for (int j = 0; j < 4; ++j) acc[i][j] = (f32x4){0.f, 0.f, 0.f, 0.f};
#pragma unroll
  for (int nb = 0; nb < 4; ++nb) {
    size_t pixblk = (size_t)blockIdx.x * 16 + w * 4 + nb;
    short8 bf[4];
#pragma unroll
    for (int kb = 0; kb < 4; ++kb) bf[kb] = gv[(pixblk * 4 + kb) * 64 + l];
#pragma unroll
    for (int mb = 0; mb < 4; ++mb)
#pragma unroll
      for (int kb = 0; kb < 4; ++kb)
        acc[mb][nb] = mfma16(af[mb][kb], bf[kb], acc[mb][nb]);
  }
#pragma unroll
  for (int mb = 0; mb < 4; ++mb)
#pragma unroll
    for (int nb = 0; nb < 4; ++nb)
#pragma unroll
      for (int r = 0; r < 4; ++r) {
        int o = mb * 16 + quad * 4 + r;
        int pix = pix0 + w * 64 + nb * 16 + ln;
        out[(size_t)o * HW + pix] = acc[mb][nb][r];
      }
}

// ---------------------------------------------------------------------------
// Workspace layout (bytes), per-batch processing to keep footprint small:
//   0          A1 (w_in frags)    32768
//   32768      A2 (w_out frags)   16384
//   49152      Mf (spectral mats) 2097152
//   2146304    gf (g frags, 1 b)  16777216
//   18923520   h  (bf16, 1 batch) 33554432
// total 52,477,952 B (~50 MiB). All offsets 16B-aligned.
// ---------------------------------------------------------------------------
extern "C" void kernel_launch(void* const* d_in, const int* in_sizes, int n_in,
                              void* d_out, int out_size, void* d_ws,
                              size_t ws_size, hipStream_t stream) {
  const float* x = (const float*)d_in[0];
  const float* w_in = (const float*)d_in[1];
  const float* w_dw = (const float*)d_in[2];
  const float* fft = (const float*)d_in[3];
  const float* w_out = (const float*)d_in[4];
  float* out = (float*)d_out;
  char* ws = (char*)d_ws;
  __hip_bfloat16* A1 = (__hip_bfloat16*)(ws);
  __hip_bfloat16* A2 = (__hip_bfloat16*)(ws + 32768);
  __hip_bfloat16* Mf = (__hip_bfloat16*)(ws + 49152);
  __hip_bfloat16* gf = (__hip_bfloat16*)(ws + 2146304);
  __hip_bfloat16* h = (__hip_bfloat16*)(ws + 18923520);

  prep_kernel<<<258, 64, 0, stream>>>(w_in, fft, w_out, A1, A2, Mf);
  for (int b = 0; b < NB; ++b) {
    const float* xb = x + (size_t)b * DIMC * HW;
    float* outb = out + (size_t)b * DIMC * HW;
    gemm1_kernel<<<1024, 256, 0, stream>>>(xb, A1, h);
    spectral_kernel<<<dim3(4, C2), 256, 0, stream>>>(h, Mf);
    dwgelu_kernel<<<dim3(16, 64), 256, 0, stream>>>(h, w_dw, gf);
    gemm2_kernel<<<256, 256, 0, stream>>>(gf, A2, outb);
  }
}

// Round 4
// 296.578 us; speedup vs baseline: 1.3200x; 1.1459x over previous
//
#include <hip/hip_runtime.h>
#include <hip/hip_bf16.h>

// Problem sizes
#define NB 4
#define DIMC 64
#define C2 256
#define HFC 128
#define HH 256
#define WW 256
#define HW (HH * WW)

typedef __attribute__((ext_vector_type(8))) short short8;
typedef __attribute__((ext_vector_type(4))) float f32x4;

__device__ __forceinline__ f32x4 mfma16(short8 a, short8 b, f32x4 c) {
  return __builtin_amdgcn_mfma_f32_16x16x32_bf16(a, b, c, 0, 0, 0);
}

__device__ __forceinline__ short f2bs(float f) {
  __hip_bfloat16 h = __float2bfloat16(f);
  union { __hip_bfloat16 h; short s; } u; u.h = h;
  return u.s;
}

__device__ __forceinline__ float bs2f(short s) {
  union { float f; unsigned u; } v;
  v.u = ((unsigned)(unsigned short)s) << 16;
  return v.f;
}

// ---------------------------------------------------------------------------
// prep: build (a) per-channel 64x64 spectral matrices from fft_filt, as MFMA
// A-fragments; (b) w_in / w_out bf16 A-fragments.
// Fragment-major layout: [mblk][kblk][lane(64)][j(8)] so a lane's 8 bf16
// A[m=lane&15][k=kblk*32+(lane>>4)*8+j] sit at byte offset lane*16.
// ---------------------------------------------------------------------------
__global__ __launch_bounds__(64) void prep_kernel(
    const float* __restrict__ w_in, const float* __restrict__ fft,
    const float* __restrict__ w_out, __hip_bfloat16* __restrict__ A1,
    __hip_bfloat16* __restrict__ A2, __hip_bfloat16* __restrict__ Mf) {
  int blk = blockIdx.x;
  int l = threadIdx.x;
  int mm = l & 15, qj = l >> 4;
  if (blk < C2) {
    __shared__ float Feff[64];
    __shared__ float kc[64];
    __shared__ float ct[8];
    if (l < 8) {
      const float s = 0.70710678118654752f;
      const float v0[8] = {1.f, s, 0.f, -s, -1.f, -s, 0.f, s};
      ct[l] = v0[l];
    }
    int c = blk;
    const float* f = fft + c * 40;  // [u][v], v in [0,5)
    int u = l >> 3, v = l & 7;
    int um = (8 - u) & 7;
    float val;
    if (v <= 4) {
      val = f[u * 5 + v];
      // pocketfft c2r ignores imag of DC/Nyquist bins -> u-symmetrize
      if (v == 0 || v == 4) val = 0.5f * (val + f[um * 5 + v]);
    } else {
      val = f[um * 5 + (8 - v)];  // Hermitian extension (filter is real)
    }
    Feff[l] = val;
    __syncthreads();
    int dy = l >> 3, dx = l & 7;
    float s = 0.f;
    for (int uu = 0; uu < 8; ++uu)
      for (int vv = 0; vv < 8; ++vv)
        s += Feff[uu * 8 + vv] * ct[(uu * dy + vv * dx) & 7];
    kc[l] = s * (1.f / 64.f);
    __syncthreads();
    for (int mb = 0; mb < 4; ++mb) {
      int p = mb * 16 + mm;
      int py = p >> 3, px = p & 7;
      for (int kb = 0; kb < 2; ++kb)
        for (int j = 0; j < 8; ++j) {
          int q = kb * 32 + qj * 8 + j;
          int qy = q >> 3, qx = q & 7;
          float kv = kc[((py - qy) & 7) * 8 + ((px - qx) & 7)];
          Mf[(size_t)c * 4096 + (size_t)((mb * 2 + kb) * 64 + l) * 8 + j] =
              __float2bfloat16(kv);
        }
    }
  } else if (blk == C2) {
    // w_in (256x64) fragments: 16 mblk x 2 kblk
    for (int mb = 0; mb < 16; ++mb)
      for (int kb = 0; kb < 2; ++kb)
        for (int j = 0; j < 8; ++j) {
          int m = mb * 16 + mm, k = kb * 32 + qj * 8 + j;
          A1[(size_t)((mb * 2 + kb) * 64 + l) * 8 + j] =
              __float2bfloat16(w_in[m * 64 + k]);
        }
  } else {
    // w_out (64x128) fragments: 4 mblk x 4 kblk
    for (int mb = 0; mb < 4; ++mb)
      for (int kb = 0; kb < 4; ++kb)
        for (int j = 0; j < 8; ++j) {
          int m = mb * 16 + mm, k = kb * 32 + qj * 8 + j;
          A2[(size_t)((mb * 4 + kb) * 64 + l) * 8 + j] =
              __float2bfloat16(w_out[m * 128 + k]);
        }
  }
}

// ---------------------------------------------------------------------------
// gemm1 (all batches): h[b][c][pix] = sum_d w_in[c][d] * x[b][d][pix], bf16.
// Block: M=256 (all channels) x N=64 pixels, K=64 whole.
// ---------------------------------------------------------------------------
__global__ __launch_bounds__(256) void gemm1_kernel(
    const float* __restrict__ x, const __hip_bfloat16* __restrict__ A1,
    __hip_bfloat16* __restrict__ h1) {
  __shared__ short Bt[8 * 64 * 8];  // [kblk*4+nblk][lane][j] = 8 KiB
  int b = blockIdx.y;
  int n0 = blockIdx.x * 64;
  int t = threadIdx.x;
  int n = t & 63, dgrp = t >> 6;
  int nblk = n >> 4, nn = n & 15;
  const float* xb = x + (size_t)b * DIMC * HW + n0 + n;
#pragma unroll
  for (int s = 0; s < 2; ++s) {
    int jb = dgrp + s * 4;  // [0,8): d-block of 8
    int kb = jb >> 2, quad = jb & 3;
    short8 pk;
#pragma unroll
    for (int j = 0; j < 8; ++j) pk[j] = f2bs(xb[(size_t)(jb * 8 + j) * HW]);
    *reinterpret_cast<short8*>(&Bt[((kb * 4 + nblk) * 64 + quad * 16 + nn) * 8]) = pk;
  }
  __syncthreads();
  int w = t >> 6, l = t & 63;
  const short8* A1v = reinterpret_cast<const short8*>(A1);
  short8 af[4][2];
#pragma unroll
  for (int mb = 0; mb < 4; ++mb)
#pragma unroll
    for (int kb = 0; kb < 2; ++kb)
      af[mb][kb] = A1v[((w * 4 + mb) * 2 + kb) * 64 + l];
  const short8* Bv = reinterpret_cast<const short8*>(Bt);
  f32x4 acc[4][4];
#pragma unroll
  for (int i = 0; i < 4; ++i)
#pragma unroll
    for (int j = 0; j < 4; ++j) acc[i][j] = (f32x4){0.f, 0.f, 0.f, 0.f};
#pragma unroll
  for (int nb = 0; nb < 4; ++nb) {
    short8 b0 = Bv[(0 * 4 + nb) * 64 + l];
    short8 b1 = Bv[(1 * 4 + nb) * 64 + l];
#pragma unroll
    for (int mb = 0; mb < 4; ++mb) {
      acc[mb][nb] = mfma16(af[mb][0], b0, acc[mb][nb]);
      acc[mb][nb] = mfma16(af[mb][1], b1, acc[mb][nb]);
    }
  }
  int quad = l >> 4, ln = l & 15;
#pragma unroll
  for (int mb = 0; mb < 4; ++mb)
#pragma unroll
    for (int nb = 0; nb < 4; ++nb)
#pragma unroll
      for (int r = 0; r < 4; ++r) {
        int m = w * 64 + mb * 16 + quad * 4 + r;
        int pix = n0 + nb * 16 + ln;
        h1[((size_t)b * C2 + m) * HW + pix] = __float2bfloat16(acc[mb][nb][r]);
      }
}

// ---------------------------------------------------------------------------
// spectral (all batches, IN-PLACE): per channel c, patch p: h <- M_c @ h.
// Each block reads only its own patches (all reads precede writes), so
// in-place is race-free; blocks never share patches.
// ---------------------------------------------------------------------------
__global__ __launch_bounds__(256) void spectral_kernel(
    __hip_bfloat16* hb, const __hip_bfloat16* __restrict__ Mf) {
  int c = blockIdx.y;
  int t0 = blockIdx.x * 256;
  int tid = threadIdx.x;
  int w = tid >> 6, l = tid & 63;
  int quad = l >> 4, ln = l & 15;
  const short8* Mv = reinterpret_cast<const short8*>(Mf + (size_t)c * 4096);
  short8 af[4][2];
#pragma unroll
  for (int mb = 0; mb < 4; ++mb)
#pragma unroll
    for (int kb = 0; kb < 2; ++kb) af[mb][kb] = Mv[(mb * 2 + kb) * 64 + l];
  f32x4 acc[4][4];
#pragma unroll
  for (int i = 0; i < 4; ++i)
#pragma unroll
    for (int j = 0; j < 4; ++j) acc[i][j] = (f32x4){0.f, 0.f, 0.f, 0.f};
#pragma unroll
  for (int nb = 0; nb < 4; ++nb) {
    int tp = t0 + w * 64 + nb * 16 + ln;  // patch id: b*1024 + Py*32 + Px
    int bb = tp >> 10, Py = (tp >> 5) & 31, Px = tp & 31;
    const __hip_bfloat16* base =
        hb + (((size_t)bb * C2 + c) * HH + Py * 8) * WW + Px * 8;
    short8 bf0 = *reinterpret_cast<const short8*>(base + (size_t)quad * WW);
    short8 bf1 = *reinterpret_cast<const short8*>(base + (size_t)(4 + quad) * WW);
#pragma unroll
    for (int mb = 0; mb < 4; ++mb) {
      acc[mb][nb] = mfma16(af[mb][0], bf0, acc[mb][nb]);
      acc[mb][nb] = mfma16(af[mb][1], bf1, acc[mb][nb]);
    }
  }
  __syncthreads();  // all reads of this block's patches complete before writes
#pragma unroll
  for (int nb = 0; nb < 4; ++nb) {
    int tp = t0 + w * 64 + nb * 16 + ln;
    int bb = tp >> 10, Py = (tp >> 5) & 31, Px = tp & 31;
    __hip_bfloat16* ob = hb + (((size_t)bb * C2 + c) * HH + Py * 8) * WW + Px * 8;
#pragma unroll
    for (int mb = 0; mb < 4; ++mb)
#pragma unroll
      for (int r = 0; r < 4; ++r) {
        int p = mb * 16 + quad * 4 + r;
        ob[(p >> 3) * WW + (p & 7)] = __float2bfloat16(acc[mb][nb][r]);
      }
  }
}

// ---------------------------------------------------------------------------
// dwgelu v3 (all batches): depthwise 3x3 (SAME) + gelu-gate, coalesced.
// Block = (jb in [0,16), y-strip of 4 rows, b). Thread t: j = t>>5 (channel
// pair c1 = jb*8+j, c2 = c1+128), xg = t&31 (8-px chunk). A wave's row loads
// cover 2 channels x 512 contiguous bytes (fully coalesced). Gated results
// land in LDS [j][r*256+px] via one b128 write per row (conflict-free);
// fragments are gathered with 8 u16 reads (2 lanes/word = free) and stored
// with 4 coalesced b128 global writes in gemm2 B-fragment layout.
// ---------------------------------------------------------------------------
__global__ __launch_bounds__(256) void dwgelu_kernel(
    const __hip_bfloat16* __restrict__ h2, const float* __restrict__ w_dw,
    __hip_bfloat16* __restrict__ gf) {
  __shared__ short ldsJ[8 * 1024];  // [j][B = r*256 + px], 16 KiB
  int jb = blockIdx.x;     // [0,16)
  int y0 = blockIdx.y * 4; // strip rows y0..y0+3
  int b = blockIdx.z;
  int t = threadIdx.x;
  int j = t >> 5, xg = t & 31;
  int x0 = xg * 8;
  int c1 = jb * 8 + j, c2 = c1 + HFC;
  const __hip_bfloat16* hbase = h2 + (size_t)b * C2 * HW;

  float wd1[9], wd2[9];
#pragma unroll
  for (int k = 0; k < 9; ++k) {
    wd1[k] = w_dw[c1 * 9 + k];
    wd2[k] = w_dw[c2 * 9 + k];
  }

  float acc1[4][8], acc2[4][8];
#pragma unroll
  for (int r = 0; r < 4; ++r)
#pragma unroll
    for (int i = 0; i < 8; ++i) { acc1[r][i] = 0.f; acc2[r][i] = 0.f; }

#pragma unroll
  for (int ir = -1; ir <= 4; ++ir) {
    int yy = y0 + ir;
    bool valid = (yy >= 0) && (yy < HH);
    float f1[10], f2[10];
    if (valid) {
      const __hip_bfloat16* r1 = hbase + ((size_t)c1 * HH + yy) * WW;
      const __hip_bfloat16* r2 = hbase + ((size_t)c2 * HH + yy) * WW;
      short8 v1 = *reinterpret_cast<const short8*>(r1 + x0);
      short8 v2 = *reinterpret_cast<const short8*>(r2 + x0);
#pragma unroll
      for (int i = 0; i < 8; ++i) { f1[i + 1] = bs2f(v1[i]); f2[i + 1] = bs2f(v2[i]); }
      f1[0] = (x0 > 0) ? __bfloat162float(r1[x0 - 1]) : 0.f;
      f2[0] = (x0 > 0) ? __bfloat162float(r2[x0 - 1]) : 0.f;
      f1[9] = (x0 + 8 < WW) ? __bfloat162float(r1[x0 + 8]) : 0.f;
      f2[9] = (x0 + 8 < WW) ? __bfloat162float(r2[x0 + 8]) : 0.f;
    } else {
#pragma unroll
      for (int i = 0; i < 10; ++i) { f1[i] = 0.f; f2[i] = 0.f; }
    }
#pragma unroll
    for (int dy = -1; dy <= 1; ++dy) {
      int r = ir - dy;
      if (r < 0 || r >= 4) continue;
      int ky = dy + 1;
#pragma unroll
      for (int i = 0; i < 8; ++i) {
        acc1[r][i] += f1[i] * wd1[ky * 3] + f1[i + 1] * wd1[ky * 3 + 1] +
                      f1[i + 2] * wd1[ky * 3 + 2];
        acc2[r][i] += f2[i] * wd2[ky * 3] + f2[i + 1] * wd2[ky * 3 + 1] +
                      f2[i + 2] * wd2[ky * 3 + 2];
      }
    }
  }

  // gate + one b128 LDS write per row (lanes contiguous: conflict-free)
#pragma unroll
  for (int r = 0; r < 4; ++r) {
    short8 pk;
#pragma unroll
    for (int i = 0; i < 8; ++i) {
      float u = acc1[r][i];
      float g = 0.5f * u * (1.f + erff(u * 0.70710678118654752f));
      pk[i] = f2bs(g * acc2[r][i]);
    }
    *reinterpret_cast<short8*>(&ldsJ[j * 1024 + r * 256 + x0]) = pk;
  }
  __syncthreads();

  // gather fragments: 8 u16 reads (2 lanes/word = free) + b128 store
  int kb = jb >> 2, quad = jb & 3;
  short8* gfv = reinterpret_cast<short8*>(gf) + (size_t)b * 1048576;
#pragma unroll
  for (int k = 0; k < 4; ++k) {
    short8 v;
#pragma unroll
    for (int j2 = 0; j2 < 8; ++j2) v[j2] = ldsJ[j2 * 1024 + k * 256 + t];
    int pix = (y0 + k) * WW + t;
    gfv[((size_t)(pix >> 4) * 4 + kb) * 64 + quad * 16 + (pix & 15)] = v;
  }
}

// ---------------------------------------------------------------------------
// gemm2 (all batches): out[b][o][pix] = sum_hf w_out[o][hf]*g[b][hf][pix].
// Block: M=64 x N=256 pixels, K=128. No LDS: fragments load coalesced.
// ---------------------------------------------------------------------------
__global__ __launch_bounds__(256) void gemm2_kernel(
    const __hip_bfloat16* __restrict__ gf, const __hip_bfloat16* __restrict__ A2,
    float* __restrict__ out) {
  int b = blockIdx.y;
  int pix0 = blockIdx.x * 256;
  int tid = threadIdx.x;
  int w = tid >> 6, l = tid & 63;
  int quad = l >> 4, ln = l & 15;
  const short8* A2v = reinterpret_cast<const short8*>(A2);
  short8 af[4][4];
#pragma unroll
  for (int mb = 0; mb < 4; ++mb)
#pragma unroll
    for (int kb = 0; kb < 4; ++kb) af[mb][kb] = A2v[(mb * 4 + kb) * 64 + l];
  const short8* gv = reinterpret_cast<const short8*>(gf) + (size_t)b * 1048576;
  f32x4 acc[4][4];
#pragma unroll
  for (int i = 0; i < 4; ++i)
#pragma unroll
    for (int j = 0; j < 4; ++j) acc[i][j] = (f32x4){0.f, 0.f, 0.f, 0.f};
#pragma unroll
  for (int nb = 0; nb < 4; ++nb) {
    size_t pixblk = (size_t)blockIdx.x * 16 + w * 4 + nb;
    short8 bf[4];
#pragma unroll
    for (int kb = 0; kb < 4; ++kb) bf[kb] = gv[(pixblk * 4 + kb) * 64 + l];
#pragma unroll
    for (int mb = 0; mb < 4; ++mb)
#pragma unroll
      for (int kb = 0; kb < 4; ++kb)
        acc[mb][nb] = mfma16(af[mb][kb], bf[kb], acc[mb][nb]);
  }
#pragma unroll
  for (int mb = 0; mb < 4; ++mb)
#pragma unroll
    for (int nb = 0; nb < 4; ++nb)
#pragma unroll
      for (int r = 0; r < 4; ++r) {
        int o = mb * 16 + quad * 4 + r;
        int pix = pix0 + w * 64 + nb * 16 + ln;
        out[((size_t)b * DIMC + o) * HW + pix] = acc[mb][nb][r];
      }
}

// ---------------------------------------------------------------------------
// Workspace layout (bytes). ws_size = 256 MiB (harness poison = 262144 KB):
//   0          A1 (w_in frags)     32768
//   32768      A2 (w_out frags)    16384
//   49152      Mf (spectral mats)  2097152
//   2146304    gf (g frags, 4 b)   67108864
//   69255168   h  (bf16, 4 b)      134217728
// total 203,472,896 B (~194 MiB) <= 256 MiB. All offsets 16B-aligned.
// ---------------------------------------------------------------------------
extern "C" void kernel_launch(void* const* d_in, const int* in_sizes, int n_in,
                              void* d_out, int out_size, void* d_ws,
                              size_t ws_size, hipStream_t stream) {
  const float* x = (const float*)d_in[0];
  const float* w_in = (const float*)d_in[1];
  const float* w_dw = (const float*)d_in[2];
  const float* fft = (const float*)d_in[3];
  const float* w_out = (const float*)d_in[4];
  float* out = (float*)d_out;
  char* ws = (char*)d_ws;
  __hip_bfloat16* A1 = (__hip_bfloat16*)(ws);
  __hip_bfloat16* A2 = (__hip_bfloat16*)(ws + 32768);
  __hip_bfloat16* Mf = (__hip_bfloat16*)(ws + 49152);
  __hip_bfloat16* gf = (__hip_bfloat16*)(ws + 2146304);
  __hip_bfloat16* h = (__hip_bfloat16*)(ws + 69255168);

  prep_kernel<<<258, 64, 0, stream>>>(w_in, fft, w_out, A1, A2, Mf);
  gemm1_kernel<<<dim3(1024, NB), 256, 0, stream>>>(x, A1, h);
  spectral_kernel<<<dim3(16, C2), 256, 0, stream>>>(h, Mf);
  dwgelu_kernel<<<dim3(16, 64, NB), 256, 0, stream>>>(h, w_dw, gf);
  gemm2_kernel<<<dim3(256, NB), 256, 0, stream>>>(gf, A2, out);
}